// Round 7
// baseline (229.565 us; speedup 1.0000x reference)
//
#include <hip/hip_runtime.h>
#include <cstdint>

#define LDP 136          // padded LDS row stride in bf16 elems (272B, 16B-aligned)
#define INFV 3.0e38f

typedef short bf16x8 __attribute__((ext_vector_type(8)));
typedef float f32x4  __attribute__((ext_vector_type(4)));

__device__ inline float bf2f(uint32_t bits){
  return __builtin_bit_cast(float, bits << 16);
}
__device__ inline ushort f2bf(float f){
  uint32_t u = __builtin_bit_cast(uint32_t, f);
  u += 0x7fffu + ((u >> 16) & 1u);   // round-to-nearest-even
  return (ushort)(u >> 16);
}

// ---- DPP helper: VALU cross-lane ------------------------------------------
#define DPPF(x, oldv, ctrl) \
  __builtin_bit_cast(float, __builtin_amdgcn_update_dpp( \
      __builtin_bit_cast(int,(oldv)), __builtin_bit_cast(int,(x)), \
      (ctrl), 0xf, 0xf, false))

__device__ inline float rl(float v, int l){    // readlane (uniform, VALU)
  return __builtin_bit_cast(float, __builtin_amdgcn_readlane(__builtin_bit_cast(int, v), l));
}

// ---------------------------------------------------------------------------
// Kernel 1: cost[b][i][j] = ||s1[b,i]||^2 + ||s2[b,j]||^2 - 2*dot  (bf16 out)
// (unchanged — proven correct since R1)
// ---------------------------------------------------------------------------
__global__ __launch_bounds__(256) void dtw_cost_gemm(
    const float* __restrict__ s1, const float* __restrict__ s2,
    ushort* __restrict__ cost)
{
  __shared__ ushort As[128*LDP];
  __shared__ ushort Bs[128*LDP];
  __shared__ float  n1s[128];
  __shared__ float  n2s[128];

  const int b  = blockIdx.y;
  const int ti = blockIdx.x / 3;
  const int tj = blockIdx.x % 3;
  const int t  = threadIdx.x;

  {
    const int row = t >> 1;
    const int par = t & 1;
    const float* Arow = s1 + ((size_t)(b*384 + ti*128 + row)) * 128;
    const float* Brow = s2 + ((size_t)(b*384 + tj*128 + row)) * 128;
    ushort* Asr = As + row*LDP;
    ushort* Bsr = Bs + row*LDP;
#pragma unroll
    for (int q = 0; q < 16; q++){
      const int col = ((2*q + par + 15*row) & 31) * 4;
      float4 va = *(const float4*)(Arow + col);
      float4 vb = *(const float4*)(Brow + col);
      ushort4 ua = make_ushort4(f2bf(va.x), f2bf(va.y), f2bf(va.z), f2bf(va.w));
      ushort4 ub = make_ushort4(f2bf(vb.x), f2bf(vb.y), f2bf(vb.z), f2bf(vb.w));
      *(ushort4*)(Asr + col) = ua;
      *(ushort4*)(Bsr + col) = ub;
    }
  }
  __syncthreads();

  {
    const ushort* rowp = (t < 128) ? (As + t*LDP) : (Bs + (t-128)*LDP);
    float s = 0.0f;
#pragma unroll
    for (int e = 0; e < 128; e += 8){
      bf16x8 v = *(const bf16x8*)(rowp + e);
#pragma unroll
      for (int k = 0; k < 8; k++){
        float f = bf2f((uint16_t)v[k]);
        s += f*f;
      }
    }
    if (t < 128) n1s[t] = s; else n2s[t-128] = s;
  }
  __syncthreads();

  const int lane = t & 63;
  const int wid  = t >> 6;
  const int wr = wid >> 1, wc = wid & 1;
  const int lrow = lane & 15;
  const int lk   = lane >> 4;

  f32x4 acc[4][4] = {};
#pragma unroll
  for (int kk = 0; kk < 4; kk++){
    const int kb = kk*32 + lk*8;
    bf16x8 af[4], bfv[4];
#pragma unroll
    for (int f = 0; f < 4; f++){
      af[f]  = *(const bf16x8*)(As + (wr*64 + f*16 + lrow)*LDP + kb);
      bfv[f] = *(const bf16x8*)(Bs + (wc*64 + f*16 + lrow)*LDP + kb);
    }
#pragma unroll
    for (int i = 0; i < 4; i++)
#pragma unroll
      for (int j = 0; j < 4; j++)
        acc[i][j] = __builtin_amdgcn_mfma_f32_16x16x32_bf16(af[i], bfv[j], acc[i][j], 0, 0, 0);
  }

  ushort* Cb = cost + (size_t)b * 147456;  // 384*384
  const int i0 = ti*128 + wr*64;
  const int j0 = tj*128 + wc*64;
  float n2v[4];
#pragma unroll
  for (int fj = 0; fj < 4; fj++) n2v[fj] = n2s[wc*64 + fj*16 + lrow];
#pragma unroll
  for (int fi = 0; fi < 4; fi++){
#pragma unroll
    for (int r = 0; r < 4; r++){
      const int il = wr*64 + fi*16 + lk*4 + r;
      const int i  = i0 + fi*16 + lk*4 + r;
      const float n1v = n1s[il];
#pragma unroll
      for (int fj = 0; fj < 4; fj++){
        float cv = n1v + n2v[fj] - 2.0f*acc[fi][fj][r];
        Cb[(size_t)i*384 + (j0 + fj*16 + lrow)] = f2bf(cv);
      }
    }
  }
}

// ---------------------------------------------------------------------------
// Kernel 2: DTW DP — anti-diagonal wavefront, PLAIN loads (compiler-tracked
// vmcnt; the R5 asm-load register-lifetime hazard is gone). One wave/batch,
// j = 6*lane + s. D_d[j] = c(d-j,j) + min3(Dm1[j], Dm1[j-1], Dm2[j-1]);
// only slot 0 needs cross-lane values (DPP row_shr:1 + 3 readlane fixups).
// Invalid cells (i<0 or i>383) stay ~INF by induction; clamped addresses
// only ever feed invalid cells. Active gather lines fit L1 (24.5 KB).
// ---------------------------------------------------------------------------
__global__ __launch_bounds__(64, 1) void dtw_dp(
    const ushort* __restrict__ cost, float* __restrict__ partial)
{
  const int b    = blockIdx.x;
  const int lane = threadIdx.x;
  const ushort* Cp = cost + (size_t)b * 147456;
  const int MAXE = 147455;

  // element offset of (i=d-j, j): 384*d - 383*j
  const int jb = 6*lane;
  const int vo0 = -383*(jb+0), vo1 = -383*(jb+1), vo2 = -383*(jb+2),
            vo3 = -383*(jb+3), vo4 = -383*(jb+4), vo5 = -383*(jb+5);

#define CLD(vo) ({ int o_ = eb + (vo); \
                   o_ = o_ < 0 ? 0 : o_; o_ = o_ > MAXE ? MAXE : o_; \
                   (uint32_t)Cp[o_]; })

  // ring: 4 named sets, set X holds diag (4m + X+1)
  uint32_t A0,A1,A2,A3,A4,A5, E0,E1,E2,E3,E4,E5,
           F0,F1,F2,F3,F4,F5, H0,H1,H2,H3,H4,H5;
  int eb;
  eb = 384*1; A0=CLD(vo0); A1=CLD(vo1); A2=CLD(vo2); A3=CLD(vo3); A4=CLD(vo4); A5=CLD(vo5);
  eb = 384*2; E0=CLD(vo0); E1=CLD(vo1); E2=CLD(vo2); E3=CLD(vo3); E4=CLD(vo4); E5=CLD(vo5);
  eb = 384*3; F0=CLD(vo0); F1=CLD(vo1); F2=CLD(vo2); F3=CLD(vo3); F4=CLD(vo4); F5=CLD(vo5);
  eb = 384*4; H0=CLD(vo0); H1=CLD(vo1); H2=CLD(vo2); H3=CLD(vo3); H4=CLD(vo4); H5=CLD(vo5);

  float r0,r1,r2,r3,r4,r5;     // D at diag d-1
  float q0,q1,q2,q3,q4,q5;     // D at diag d-2
  float shR, shQ;              // prev-lane slot-5 of r / q

  // diag 0: only (0,0) valid
  r0 = (lane == 0) ? bf2f((uint32_t)Cp[0]) : INFV;
  r1=r2=r3=r4=r5=INFV;
  q0=q1=q2=q3=q4=q5=INFV;
  shR = INFV; shQ = INFV;

  eb = 384*5;   // next prefetch target

#define STEP(S0,S1,S2,S3,S4,S5) do { \
    float c0=bf2f(S0), c1=bf2f(S1), c2=bf2f(S2), \
          c3=bf2f(S3), c4=bf2f(S4), c5=bf2f(S5); \
    S0=CLD(vo0); S1=CLD(vo1); S2=CLD(vo2); \
    S3=CLD(vo3); S4=CLD(vo4); S5=CLD(vo5); \
    eb += 384; \
    float n0 = c0 + fminf(fminf(r0, shR), shQ); \
    float n1 = c1 + fminf(fminf(r1, r0), q0); \
    float n2 = c2 + fminf(fminf(r2, r1), q1); \
    float n3 = c3 + fminf(fminf(r3, r2), q2); \
    float n4 = c4 + fminf(fminf(r4, r3), q3); \
    float n5 = c5 + fminf(fminf(r5, r4), q4); \
    float sh_ = DPPF(n5, INFV, 0x111); \
    sh_ = (lane==16) ? rl(n5,15) : sh_; \
    sh_ = (lane==32) ? rl(n5,31) : sh_; \
    sh_ = (lane==48) ? rl(n5,47) : sh_; \
    q0=r0; q1=r1; q2=r2; q3=r3; q4=r4; q5=r5; \
    r0=n0; r1=n1; r2=n2; r3=n3; r4=n4; r5=n5; \
    shQ = shR; shR = sh_; \
  } while(0)

  // main: 191 iters x 4 = diagonals 1..764
  for (int k = 0; k < 191; ++k){
    STEP(A0,A1,A2,A3,A4,A5);   // d = 4k+1
    STEP(E0,E1,E2,E3,E4,E5);   // d = 4k+2
    STEP(F0,F1,F2,F3,F4,F5);   // d = 4k+3
    STEP(H0,H1,H2,H3,H4,H5);   // d = 4k+4
  }
  // tail: d = 765, 766
  STEP(A0,A1,A2,A3,A4,A5);
  STEP(E0,E1,E2,E3,E4,E5);

  if (lane == 63) partial[b] = r5;             // D[383][383]

#undef STEP
#undef CLD
}

// ---------------------------------------------------------------------------
// Kernel 3: mean of 128 partials -> out[0]
// ---------------------------------------------------------------------------
__global__ __launch_bounds__(64) void dtw_reduce(
    const float* __restrict__ partial, float* __restrict__ out)
{
  const int l = threadIdx.x;
  float v = partial[l] + partial[l + 64];
#pragma unroll
  for (int d = 32; d >= 1; d >>= 1) v += __shfl_xor(v, d, 64);
  if (l == 0) out[0] = v * (1.0f/128.0f);
}

extern "C" void kernel_launch(void* const* d_in, const int* in_sizes, int n_in,
                              void* d_out, int out_size, void* d_ws, size_t ws_size,
                              hipStream_t stream)
{
  (void)in_sizes; (void)n_in; (void)out_size; (void)ws_size;
  const float* s1 = (const float*)d_in[0];
  const float* s2 = (const float*)d_in[1];
  float* out = (float*)d_out;

  ushort* cost    = (ushort*)d_ws;                                   // 128*384*384*2 B
  float*  partial = (float*)((char*)d_ws + (size_t)128*147456*2);    // 128 floats

  dtw_cost_gemm<<<dim3(9, 128), dim3(256), 0, stream>>>(s1, s2, cost);
  dtw_dp<<<dim3(128), dim3(64), 0, stream>>>(cost, partial);
  dtw_reduce<<<dim3(1), dim3(64), 0, stream>>>(partial, out);
}

// Round 8
// 221.479 us; speedup vs baseline: 1.0365x; 1.0365x over previous
//
#include <hip/hip_runtime.h>
#include <cstdint>

#define LDP 136          // padded LDS row stride in bf16 elems (272B, 16B-aligned)
#define INFV 3.0e38f
#define CB_STRIDE 147840 // padded diag-major cost elems per batch

typedef short bf16x8 __attribute__((ext_vector_type(8)));
typedef float f32x4  __attribute__((ext_vector_type(4)));

__device__ inline float bf2f(uint32_t bits){
  return __builtin_bit_cast(float, bits << 16);
}
__device__ inline float bf2f_lo(uint32_t w){ return __builtin_bit_cast(float, w << 16); }
__device__ inline float bf2f_hi(uint32_t w){ return __builtin_bit_cast(float, w & 0xffff0000u); }
__device__ inline ushort f2bf(float f){
  uint32_t u = __builtin_bit_cast(uint32_t, f);
  u += 0x7fffu + ((u >> 16) & 1u);   // round-to-nearest-even
  return (ushort)(u >> 16);
}

// ---- DPP helper: VALU cross-lane ------------------------------------------
#define DPPF(x, oldv, ctrl) \
  __builtin_bit_cast(float, __builtin_amdgcn_update_dpp( \
      __builtin_bit_cast(int,(oldv)), __builtin_bit_cast(int,(x)), \
      (ctrl), 0xf, 0xf, false))

__device__ inline float rl(float v, int l){    // readlane (uniform, VALU)
  return __builtin_bit_cast(float, __builtin_amdgcn_readlane(__builtin_bit_cast(int, v), l));
}

// diag-major compact offset of cell (i,j), with even-padding per diag so
// every diag's slot-0 element index (start' - jmin) is EVEN (4B-aligned).
__device__ inline int diag_off(int i, int j){
  const int d = i + j;
  if (d <= 383){
    return ((d*(d+1))>>1) + ((d+1)>>1) + j;
  } else {
    const int e2 = 767 - d;
    return 147456 - ((e2*(e2+1))>>1) + 193 + ((d-384)>>1) + j - (d-383);
  }
}

// ---------------------------------------------------------------------------
// Kernel 1: cost GEMM (bf16 MFMA) with diag-major epilogue stores.
// ---------------------------------------------------------------------------
__global__ __launch_bounds__(256) void dtw_cost_gemm(
    const float* __restrict__ s1, const float* __restrict__ s2,
    ushort* __restrict__ cost)
{
  __shared__ ushort As[128*LDP];
  __shared__ ushort Bs[128*LDP];
  __shared__ float  n1s[128];
  __shared__ float  n2s[128];

  const int b  = blockIdx.y;
  const int ti = blockIdx.x / 3;
  const int tj = blockIdx.x % 3;
  const int t  = threadIdx.x;

  {
    const int row = t >> 1;
    const int par = t & 1;
    const float* Arow = s1 + ((size_t)(b*384 + ti*128 + row)) * 128;
    const float* Brow = s2 + ((size_t)(b*384 + tj*128 + row)) * 128;
    ushort* Asr = As + row*LDP;
    ushort* Bsr = Bs + row*LDP;
#pragma unroll
    for (int q = 0; q < 16; q++){
      const int col = ((2*q + par + 15*row) & 31) * 4;
      float4 va = *(const float4*)(Arow + col);
      float4 vb = *(const float4*)(Brow + col);
      ushort4 ua = make_ushort4(f2bf(va.x), f2bf(va.y), f2bf(va.z), f2bf(va.w));
      ushort4 ub = make_ushort4(f2bf(vb.x), f2bf(vb.y), f2bf(vb.z), f2bf(vb.w));
      *(ushort4*)(Asr + col) = ua;
      *(ushort4*)(Bsr + col) = ub;
    }
  }
  __syncthreads();

  {
    const ushort* rowp = (t < 128) ? (As + t*LDP) : (Bs + (t-128)*LDP);
    float s = 0.0f;
#pragma unroll
    for (int e = 0; e < 128; e += 8){
      bf16x8 v = *(const bf16x8*)(rowp + e);
#pragma unroll
      for (int k = 0; k < 8; k++){
        float f = bf2f((uint16_t)v[k]);
        s += f*f;
      }
    }
    if (t < 128) n1s[t] = s; else n2s[t-128] = s;
  }
  __syncthreads();

  const int lane = t & 63;
  const int wid  = t >> 6;
  const int wr = wid >> 1, wc = wid & 1;
  const int lrow = lane & 15;
  const int lk   = lane >> 4;

  f32x4 acc[4][4] = {};
#pragma unroll
  for (int kk = 0; kk < 4; kk++){
    const int kb = kk*32 + lk*8;
    bf16x8 af[4], bfv[4];
#pragma unroll
    for (int f = 0; f < 4; f++){
      af[f]  = *(const bf16x8*)(As + (wr*64 + f*16 + lrow)*LDP + kb);
      bfv[f] = *(const bf16x8*)(Bs + (wc*64 + f*16 + lrow)*LDP + kb);
    }
#pragma unroll
    for (int i = 0; i < 4; i++)
#pragma unroll
      for (int j = 0; j < 4; j++)
        acc[i][j] = __builtin_amdgcn_mfma_f32_16x16x32_bf16(af[i], bfv[j], acc[i][j], 0, 0, 0);
  }

  ushort* Cb = cost + (size_t)b * CB_STRIDE;
  const int i0 = ti*128 + wr*64;
  const int j0 = tj*128 + wc*64;
  float n2v[4];
#pragma unroll
  for (int fj = 0; fj < 4; fj++) n2v[fj] = n2s[wc*64 + fj*16 + lrow];
#pragma unroll
  for (int fi = 0; fi < 4; fi++){
#pragma unroll
    for (int r = 0; r < 4; r++){
      const int il = wr*64 + fi*16 + lk*4 + r;
      const int i  = i0 + fi*16 + lk*4 + r;
      const float n1v = n1s[il];
#pragma unroll
      for (int fj = 0; fj < 4; fj++){
        float cv = n1v + n2v[fj] - 2.0f*acc[fi][fj][r];
        const int col = j0 + fj*16 + lrow;
        Cb[diag_off(i, col)] = f2bf(cv);
      }
    }
  }
}

// ---------------------------------------------------------------------------
// Kernel 2: DTW DP — anti-diagonal wavefront over diag-major cost.
// Coalesced: diag d is contiguous (12B/lane). Staged via global_load_lds
// into a 4-slot LDS ring, counted vmcnt (asm w/ memory clobber orders all
// memory ops; pure DP math floats free). 1-step ds_read-ahead in W regs.
// ---------------------------------------------------------------------------
__global__ __launch_bounds__(64, 1) void dtw_dp(
    const ushort* __restrict__ cost, float* __restrict__ partial)
{
  __shared__ uint32_t lds[4*192];
  const int b    = blockIdx.x;
  const int lane = threadIdx.x;
  const ushort* Cp = cost + (size_t)b * CB_STRIDE;

  typedef __attribute__((address_space(1))) const uint32_t GU32;
  typedef __attribute__((address_space(3))) uint32_t LU32;

#define STAGE(sl, spf_) do { \
    const char* gb_ = (const char*)Cp + 2*(spf_) + 4*lane; \
    __builtin_amdgcn_global_load_lds((GU32*)(gb_      ), (LU32*)&lds[(sl)*192      ], 4, 0, 0); \
    __builtin_amdgcn_global_load_lds((GU32*)(gb_ + 256), (LU32*)&lds[(sl)*192 +  64], 4, 0, 0); \
    __builtin_amdgcn_global_load_lds((GU32*)(gb_ + 512), (LU32*)&lds[(sl)*192 + 128], 4, 0, 0); \
  } while(0)

#define WAIT_VM(n) do { \
    asm volatile("s_waitcnt vmcnt(" #n ")" ::: "memory"); \
    __builtin_amdgcn_sched_barrier(0); \
  } while(0)
#define WAIT_LG() do { \
    asm volatile("s_waitcnt lgkmcnt(0)" ::: "memory"); \
    __builtin_amdgcn_sched_barrier(0); \
  } while(0)

  float r0,r1,r2,r3,r4,r5;     // D at diag d-1
  float q0,q1,q2,q3,q4,q5;     // D at diag d-2
  float shR, shQ;              // prev-lane slot-5 of r / q
  uint32_t W0, W1, W2;         // current diag's 6 costs (ds_read'd last step)

#define BODYX() do { \
    float c0=bf2f_lo(W0), c1=bf2f_hi(W0), c2=bf2f_lo(W1), \
          c3=bf2f_hi(W1), c4=bf2f_lo(W2), c5=bf2f_hi(W2); \
    float n0 = c0 + fminf(fminf(r0, shR), shQ); \
    float n1 = c1 + fminf(fminf(r1, r0), q0); \
    float n2 = c2 + fminf(fminf(r2, r1), q1); \
    float n3 = c3 + fminf(fminf(r3, r2), q2); \
    float n4 = c4 + fminf(fminf(r4, r3), q3); \
    float n5 = c5 + fminf(fminf(r5, r4), q4); \
    float sh_ = DPPF(n5, INFV, 0x111); \
    sh_ = (lane==16) ? rl(n5,15) : sh_; \
    sh_ = (lane==32) ? rl(n5,31) : sh_; \
    sh_ = (lane==48) ? rl(n5,47) : sh_; \
    q0=r0; q1=r1; q2=r2; q3=r3; q4=r4; q5=r5; \
    r0=n0; r1=n1; r2=n2; r3=n3; r4=n4; r5=n5; \
    shQ = shR; shR = sh_; \
  } while(0)

  // one full step at diag d: consume W(d), stage d+4, read-ahead W(d+1)
#define STEPX(slw, slr) do { \
    BODYX(); \
    WAIT_LG(); \
    STAGE(slw, spf); \
    { int sl_ = (pd < 383) ? (pd + 1 + ((pd & 1) ^ 1)) \
              : (pd == 383) ? 385 : (767 - pd) + (pd & 1); \
      spf += sl_ - (pd >= 383 ? 1 : 0); pd++; \
      if (pd > 766){ pd = 766; spf = 147456; } } \
    WAIT_VM(9); \
    W0 = lds[(slr)*192 + 3*lane    ]; \
    W1 = lds[(slr)*192 + 3*lane + 1]; \
    W2 = lds[(slr)*192 + 3*lane + 2]; \
  } while(0)

  // ---- prologue: stage diags 1..4 (sbase' = 2,4,8,12); diag 0 is elem 0 ----
  int pd = 5, spf = 18;        // next prefetch diag and its sbase'
  STAGE(1, 2); STAGE(2, 4); STAGE(3, 8); STAGE(0, 12);

  r0 = (lane == 0) ? bf2f((uint32_t)Cp[0]) : INFV;
  r1=r2=r3=r4=r5=INFV;
  q0=q1=q2=q3=q4=q5=INFV;
  shR = INFV; shQ = INFV;

  WAIT_VM(9);                  // diag 1 staged
  W0 = lds[1*192 + 3*lane]; W1 = lds[1*192 + 3*lane + 1]; W2 = lds[1*192 + 3*lane + 2];

  // ---- main: 191 iters x 4 steps = diagonals 1..764 ----
  for (int k = 0; k < 191; ++k){
    STEPX(1, 2);   // d = 4k+1: stage slot 1, read diag d+1 from slot 2
    STEPX(2, 3);   // d = 4k+2
    STEPX(3, 0);   // d = 4k+3
    STEPX(0, 1);   // d = 4k+4
  }

  // ---- tail: d = 765 (W ready), then d = 766 from slot 2 ----
  BODYX();
  WAIT_VM(6);
  W0 = lds[2*192 + 3*lane]; W1 = lds[2*192 + 3*lane + 1]; W2 = lds[2*192 + 3*lane + 2];
  WAIT_LG();
  BODYX();

  if (lane == 63) partial[b] = r5;             // D[383][383]

#undef STEPX
#undef BODYX
#undef STAGE
#undef WAIT_VM
#undef WAIT_LG
}

// ---------------------------------------------------------------------------
// Kernel 3: mean of 128 partials -> out[0]
// ---------------------------------------------------------------------------
__global__ __launch_bounds__(64) void dtw_reduce(
    const float* __restrict__ partial, float* __restrict__ out)
{
  const int l = threadIdx.x;
  float v = partial[l] + partial[l + 64];
#pragma unroll
  for (int d = 32; d >= 1; d >>= 1) v += __shfl_xor(v, d, 64);
  if (l == 0) out[0] = v * (1.0f/128.0f);
}

extern "C" void kernel_launch(void* const* d_in, const int* in_sizes, int n_in,
                              void* d_out, int out_size, void* d_ws, size_t ws_size,
                              hipStream_t stream)
{
  (void)in_sizes; (void)n_in; (void)out_size; (void)ws_size;
  const float* s1 = (const float*)d_in[0];
  const float* s2 = (const float*)d_in[1];
  float* out = (float*)d_out;

  ushort* cost    = (ushort*)d_ws;                                     // 128*147840*2 B
  float*  partial = (float*)((char*)d_ws + (size_t)128*CB_STRIDE*2);   // 128 floats

  dtw_cost_gemm<<<dim3(9, 128), dim3(256), 0, stream>>>(s1, s2, cost);
  dtw_dp<<<dim3(128), dim3(64), 0, stream>>>(cost, partial);
  dtw_reduce<<<dim3(1), dim3(64), 0, stream>>>(partial, out);
}